// Round 1
// baseline (519.176 us; speedup 1.0000x reference)
//
#include <hip/hip_runtime.h>

#define N_NODES 100000
#define N_EDGES 1280000
#define D 64

// Kernel 1: zero the accumulator (d_out doubles as summed[]) and counts (in ws).
__global__ void zero_kernel(float* __restrict__ summed, float* __restrict__ cnt) {
    int stride = gridDim.x * blockDim.x;
    int i = blockIdx.x * blockDim.x + threadIdx.x;
    const int total = N_NODES * D;
    for (int idx = i; idx < total; idx += stride) summed[idx] = 0.0f;
    for (int idx = i; idx < N_NODES; idx += stride) cnt[idx] = 0.0f;
}

// Kernel 2: edge-parallel scatter-add. 64 consecutive threads handle one edge:
// coalesced read of x[col] row (256B), coalesced atomicAdd into summed[row].
__global__ void scatter_kernel(const float* __restrict__ x,
                               const int* __restrict__ row,
                               const int* __restrict__ col,
                               float* __restrict__ summed,
                               float* __restrict__ cnt) {
    long long gid = (long long)blockIdx.x * blockDim.x + threadIdx.x;
    const long long total = (long long)N_EDGES * D;
    if (gid >= total) return;
    int e = (int)(gid >> 6);
    int f = (int)(gid & 63);
    int r = row[e];
    int c = col[e];
    atomicAdd(&summed[r * D + f], x[c * D + f]);
    if (f == 0) atomicAdd(&cnt[r], 1.0f);
}

// Kernel 3: per-row epilogue. 4 rows per 256-thread block; each 64-lane group
// owns one row. Read summed row (from d_out), divide by count -> agg, stage
// agg and x row in LDS, then thread f computes output feature f:
//   out[f] = bias[f] + sum_k agg[k]*W[k][f] + x[k]*Wr[k][f]
// In-place on d_out is safe: only this block touches row r, barrier between
// the read and the write.
__global__ void finish_kernel(const float* __restrict__ x,
                              const float* __restrict__ W,
                              const float* __restrict__ Wr,
                              const float* __restrict__ bias,
                              const float* __restrict__ cnt,
                              float* __restrict__ out) {
    __shared__ float agg_s[4][D];
    __shared__ float x_s[4][D];
    int lrow = threadIdx.x >> 6;
    int f = threadIdx.x & 63;
    int r = blockIdx.x * 4 + lrow;

    float aggv = 0.0f, xv = 0.0f;
    if (r < N_NODES) {
        float c = cnt[r];
        float inv = 1.0f / fmaxf(c, 1.0f);
        aggv = out[r * D + f] * inv;
        xv = x[r * D + f];
    }
    agg_s[lrow][f] = aggv;
    x_s[lrow][f] = xv;
    __syncthreads();
    if (r >= N_NODES) return;

    float acc = bias[f];
#pragma unroll 8
    for (int k = 0; k < D; ++k) {
        // agg_s[lrow][k]: same address across the wave -> LDS broadcast, free.
        // W[k*D+f]: consecutive lanes consecutive addresses, 16KB -> L1/L2 hit.
        acc += agg_s[lrow][k] * W[k * D + f];
        acc += x_s[lrow][k] * Wr[k * D + f];
    }
    out[r * D + f] = acc;
}

extern "C" void kernel_launch(void* const* d_in, const int* in_sizes, int n_in,
                              void* d_out, int out_size, void* d_ws, size_t ws_size,
                              hipStream_t stream) {
    const float* x    = (const float*)d_in[0];
    const int*   ei   = (const int*)d_in[1];   // [2, E]: row = ei, col = ei + E
    const float* W    = (const float*)d_in[2];
    const float* Wr   = (const float*)d_in[3];
    const float* bias = (const float*)d_in[4];

    float* out = (float*)d_out;          // doubles as summed[] accumulator
    float* cnt = (float*)d_ws;           // N_NODES floats (400 KB)

    const int* row = ei;
    const int* col = ei + N_EDGES;

    // 1) zero accumulator + counts
    zero_kernel<<<4096, 256, 0, stream>>>(out, cnt);

    // 2) scatter: E*64 threads
    {
        long long total = (long long)N_EDGES * D;
        int blocks = (int)((total + 255) / 256);
        scatter_kernel<<<blocks, 256, 0, stream>>>(x, row, col, out, cnt);
    }

    // 3) mean + dual GEMM epilogue, in place
    {
        int blocks = (N_NODES + 3) / 4;
        finish_kernel<<<blocks, 256, 0, stream>>>(x, W, Wr, bias, cnt, out);
    }
}

// Round 3
// 395.192 us; speedup vs baseline: 1.3137x; 1.3137x over previous
//
#include <hip/hip_runtime.h>

#define N_NODES 100000
#define N_EDGES 1280000
#define D 64
#define NB ((N_NODES + 255) / 256)   // 391 scan blocks

// ==================== CSR path (needs ~5.92 MB ws) ====================

__global__ void zero_deg_kernel(int* __restrict__ deg) {
    int i = blockIdx.x * blockDim.x + threadIdx.x;
    if (i < N_NODES) deg[i] = 0;
}

__global__ void hist_kernel(const int* __restrict__ row, int* __restrict__ deg) {
    int e = blockIdx.x * blockDim.x + threadIdx.x;
    if (e < N_EDGES) atomicAdd(&deg[row[e]], 1);
}

// Per-block exclusive scan of deg -> cursor, block totals -> bsum.
__global__ void scan_block_kernel(const int* __restrict__ deg,
                                  int* __restrict__ cursor,
                                  int* __restrict__ bsum) {
    __shared__ int s[256];
    int tid = threadIdx.x;
    int gid = blockIdx.x * 256 + tid;
    int v = (gid < N_NODES) ? deg[gid] : 0;
    s[tid] = v;
    __syncthreads();
    for (int d = 1; d < 256; d <<= 1) {
        int t = (tid >= d) ? s[tid - d] : 0;
        __syncthreads();
        s[tid] += t;
        __syncthreads();
    }
    if (gid < N_NODES) cursor[gid] = s[tid] - v;       // exclusive
    if (tid == 255) bsum[blockIdx.x] = s[255];
}

// Single-block exclusive scan of the NB block sums (NB=391 <= 512).
__global__ void scan_bsum_kernel(int* __restrict__ bsum) {
    __shared__ int s[512];
    int tid = threadIdx.x;
    int v = (tid < NB) ? bsum[tid] : 0;
    s[tid] = v;
    __syncthreads();
    for (int d = 1; d < 512; d <<= 1) {
        int t = (tid >= d) ? s[tid - d] : 0;
        __syncthreads();
        s[tid] += t;
        __syncthreads();
    }
    if (tid < NB) bsum[tid] = s[tid] - v;              // exclusive
}

__global__ void add_offsets_kernel(int* __restrict__ cursor,
                                   const int* __restrict__ bsum) {
    int gid = blockIdx.x * 256 + threadIdx.x;
    if (gid < N_NODES) cursor[gid] += bsum[blockIdx.x];
}

// Scatter edges into CSR order. After this, cursor[r] == END offset of node r
// (start = cursor[r] - deg[r]).
__global__ void scatter_build_kernel(const int* __restrict__ row,
                                     const int* __restrict__ col,
                                     int* __restrict__ cursor,
                                     int* __restrict__ col_sorted) {
    int e = blockIdx.x * blockDim.x + threadIdx.x;
    if (e < N_EDGES) {
        int r = row[e];
        int p = atomicAdd(&cursor[r], 1);
        col_sorted[p] = col[e];
    }
}

// Fused gather-aggregate + mean + dual GEMM. 4 wave-groups of 64 per block;
// each group owns one node row; lane f owns feature f.
__launch_bounds__(256)
__global__ void aggregate_kernel(const float* __restrict__ x,
                                 const int* __restrict__ cursor_end,
                                 const int* __restrict__ deg,
                                 const int* __restrict__ col_sorted,
                                 const float* __restrict__ W,
                                 const float* __restrict__ Wr,
                                 const float* __restrict__ bias,
                                 float* __restrict__ out) {
    __shared__ float Ws[D * D];
    __shared__ float Wrs[D * D];
    __shared__ float agg_s[4][D];
    __shared__ float x_s[4][D];

    for (int i = threadIdx.x; i < D * D; i += 256) {
        Ws[i] = W[i];
        Wrs[i] = Wr[i];
    }

    int g = threadIdx.x >> 6;
    int f = threadIdx.x & 63;
    int r = blockIdx.x * 4 + g;          // N_NODES % 4 == 0: always in range

    int n = deg[r];
    int start = cursor_end[r] - n;

    float a0 = 0.f, a1 = 0.f, a2 = 0.f, a3 = 0.f;
    int j = 0;
    for (; j + 4 <= n; j += 4) {
        int c0 = col_sorted[start + j + 0];
        int c1 = col_sorted[start + j + 1];
        int c2 = col_sorted[start + j + 2];
        int c3 = col_sorted[start + j + 3];
        a0 += x[c0 * D + f];
        a1 += x[c1 * D + f];
        a2 += x[c2 * D + f];
        a3 += x[c3 * D + f];
    }
    for (; j < n; ++j) a0 += x[col_sorted[start + j] * D + f];

    float inv = 1.0f / (float)(n > 1 ? n : 1);
    float agg = ((a0 + a1) + (a2 + a3)) * inv;
    float xv = x[r * D + f];

    agg_s[g][f] = agg;
    x_s[g][f] = xv;
    __syncthreads();

    float o = bias[f];
#pragma unroll
    for (int k = 0; k < D; ++k) {
        o += agg_s[g][k] * Ws[k * D + f] + x_s[g][k] * Wrs[k * D + f];
    }
    out[r * D + f] = o;
}

// ==================== atomic fallback path (needs 400 KB ws) ====================

__global__ void zero_kernel(float* __restrict__ summed, float* __restrict__ cnt) {
    int stride = gridDim.x * blockDim.x;
    int i = blockIdx.x * blockDim.x + threadIdx.x;
    const int total = N_NODES * D;
    for (int idx = i; idx < total; idx += stride) summed[idx] = 0.0f;
    for (int idx = i; idx < N_NODES; idx += stride) cnt[idx] = 0.0f;
}

__global__ void scatter_atomic_kernel(const float* __restrict__ x,
                                      const int* __restrict__ row,
                                      const int* __restrict__ col,
                                      float* __restrict__ summed,
                                      float* __restrict__ cnt) {
    long long gid = (long long)blockIdx.x * blockDim.x + threadIdx.x;
    const long long total = (long long)N_EDGES * D;
    if (gid >= total) return;
    int e = (int)(gid >> 6);
    int f = (int)(gid & 63);
    int r = row[e];
    int c = col[e];
    atomicAdd(&summed[r * D + f], x[c * D + f]);
    if (f == 0) atomicAdd(&cnt[r], 1.0f);
}

__global__ void finish_kernel(const float* __restrict__ x,
                              const float* __restrict__ W,
                              const float* __restrict__ Wr,
                              const float* __restrict__ bias,
                              const float* __restrict__ cnt,
                              float* __restrict__ out) {
    __shared__ float agg_s[4][D];
    __shared__ float x_s[4][D];
    int lrow = threadIdx.x >> 6;
    int f = threadIdx.x & 63;
    int r = blockIdx.x * 4 + lrow;

    float c = cnt[r];
    float inv = 1.0f / fmaxf(c, 1.0f);
    float aggv = out[r * D + f] * inv;
    float xv = x[r * D + f];
    agg_s[lrow][f] = aggv;
    x_s[lrow][f] = xv;
    __syncthreads();

    float acc = bias[f];
#pragma unroll 8
    for (int k = 0; k < D; ++k) {
        acc += agg_s[lrow][k] * W[k * D + f];
        acc += x_s[lrow][k] * Wr[k * D + f];
    }
    out[r * D + f] = acc;
}

// ==================== launch ====================

extern "C" void kernel_launch(void* const* d_in, const int* in_sizes, int n_in,
                              void* d_out, int out_size, void* d_ws, size_t ws_size,
                              hipStream_t stream) {
    const float* x    = (const float*)d_in[0];
    const int*   ei   = (const int*)d_in[1];   // [2, E]: row = ei, col = ei + E
    const float* W    = (const float*)d_in[2];
    const float* Wr   = (const float*)d_in[3];
    const float* bias = (const float*)d_in[4];
    float* out = (float*)d_out;

    const int* row = ei;
    const int* col = ei + N_EDGES;

    // CSR workspace layout: deg(N) | cursor(N) | bsum(512) | col_sorted(E)
    const size_t need_csr = (size_t)2 * N_NODES * 4 + 2048 + (size_t)N_EDGES * 4;

    if (ws_size >= need_csr) {
        char* ws = (char*)d_ws;
        int* deg        = (int*)(ws);
        int* cursor     = (int*)(ws + (size_t)1 * N_NODES * 4);
        int* bsum       = (int*)(ws + (size_t)2 * N_NODES * 4);
        int* col_sorted = (int*)(ws + (size_t)2 * N_NODES * 4 + 2048);

        zero_deg_kernel<<<NB, 256, 0, stream>>>(deg);
        hist_kernel<<<(N_EDGES + 255) / 256, 256, 0, stream>>>(row, deg);
        scan_block_kernel<<<NB, 256, 0, stream>>>(deg, cursor, bsum);
        scan_bsum_kernel<<<1, 512, 0, stream>>>(bsum);
        add_offsets_kernel<<<NB, 256, 0, stream>>>(cursor, bsum);
        scatter_build_kernel<<<(N_EDGES + 255) / 256, 256, 0, stream>>>(row, col, cursor, col_sorted);
        aggregate_kernel<<<N_NODES / 4, 256, 0, stream>>>(x, cursor, deg, col_sorted, W, Wr, bias, out);
    } else {
        // atomic fallback (round-1 verified): out doubles as summed[]
        float* cnt = (float*)d_ws;   // N_NODES floats
        zero_kernel<<<4096, 256, 0, stream>>>(out, cnt);
        long long total = (long long)N_EDGES * D;
        int blocks = (int)((total + 255) / 256);
        scatter_atomic_kernel<<<blocks, 256, 0, stream>>>(x, row, col, out, cnt);
        finish_kernel<<<(N_NODES + 3) / 4, 256, 0, stream>>>(x, W, Wr, bias, cnt, out);
    }
}